// Round 21
// baseline (42.042 us; speedup 1.0000x reference)
//
#include <hip/hip_runtime.h>
#include <hip/hip_bf16.h>

// Problem constants (match reference)
#define NN 1024
#define FF 256
#define DD 64
#define RR 11
#define EE 2048
#define ALPHA 0.2f
#define TPB 512
#define EPT (EE / TPB)          // 4 edges per thread in K1
#define TILE_E 32               // edges per K2 tile (same relation)
#define PERM_CAP 2432           // >= 2048 + 11*31, = 76*32
#define K2_GRID (PERM_CAP / TILE_E)  // 76

// ws layout (bytes):
//   0     : int perm[PERM_CAP]    (9728 B)
//   12288 : int tile_rel[K2_GRID] (304 B)  relation per tile, -1 = empty
//   16384 : float cbuf[EE*FF]     (2 MB, e-major: cbuf[e*FF+f])
//
// DIAGNOSTIC ROUND 2: K2 is launched THREE times (idempotent: rewrites out
// with identical values from inputs that are stable after K1).
// dur = 19.9 + 2*(k2_inclusive). Resolves K1-internal vs per-node overhead.

// K1 (R17-verbatim)
__global__ __launch_bounds__(TPB) void k1_coef(
    const float* __restrict__ x, const float* __restrict__ W,
    const float* __restrict__ a, const int* __restrict__ src,
    const int* __restrict__ dst, const int* __restrict__ rel,
    float* __restrict__ cbuf, int* __restrict__ perm,
    int* __restrict__ tile_rel) {

    const int b    = blockIdx.x;   // 0..256
    const int tid  = threadIdx.x;  // 0..511
    const int wid  = tid >> 6;     // 0..7
    const int lane = tid & 63;

    __shared__ int hist[16], base_sh[16], off_sh[16];

    if (b == FF) {
        // dedicated sort block
        if (tid < 16) hist[tid] = 0;
        __syncthreads();
        for (int e = tid; e < EE; e += TPB) atomicAdd(&hist[rel[e]], 1);
        __syncthreads();
        if (tid == 0) {
            int acc = 0;
            for (int r = 0; r < RR; ++r) {
                base_sh[r] = acc;
                off_sh[r] = acc;
                acc += (hist[r] + TILE_E - 1) & ~(TILE_E - 1);
            }
            int r = 0;
            for (int t = 0; t < K2_GRID; ++t) {
                while (r < RR && t * TILE_E >=
                       base_sh[r] + ((hist[r] + TILE_E - 1) & ~(TILE_E - 1)))
                    ++r;
                tile_rel[t] = (r < RR &&
                               t * TILE_E < base_sh[r] +
                               ((hist[r] + TILE_E - 1) & ~(TILE_E - 1)))
                              ? r : -1;
            }
        }
        __syncthreads();
        for (int i = tid; i < PERM_CAP; i += TPB) perm[i] = -1;
        __syncthreads();
        for (int e = tid; e < EE; e += TPB) {
            int pos = atomicAdd(&off_sh[rel[e]], 1);
            perm[pos] = e;
        }
        return;
    }

    const int f = ((b & 7) << 5) | (b >> 3);   // XCD-grouped feature

    __shared__ float xcol[NN];     // 4 KB: x[:, f]
    __shared__ float p_sh[RR], q_sh[RR];
    __shared__ float red_s[8];

    // stage column f of x (lines L2-shared within this XCD)
    for (int i = tid; i < NN; i += TPB) xcol[i] = x[(size_t)i * FF + f];

    // own-feature p/q
    for (int r = wid; r < RR; r += 8) {
        float w  = W[((size_t)r * FF + f) * DD + lane];
        float pa = w * a[lane];
        float qa = w * a[DD + lane];
        #pragma unroll
        for (int o = 32; o > 0; o >>= 1) {
            pa += __shfl_down(pa, o);
            qa += __shfl_down(qa, o);
        }
        if (lane == 0) { p_sh[r] = pa; q_sh[r] = qa; }
    }
    __syncthreads();   // xcol + p_sh/q_sh ready

    // single pass: u = exp(v)*xd, s = sum(exp(v))
    float uvals[EPT];
    float s = 0.0f;
    #pragma unroll
    for (int k = 0; k < EPT; ++k) {
        int e = tid + k * TPB;
        float xs = xcol[src[e]];
        float xd = xcol[dst[e]];
        int r = rel[e];
        float v = xs * p_sh[r] + xd * q_sh[r];
        v = v > 0.0f ? v : ALPHA * v;
        float ev = expf(v);
        uvals[k] = ev * xd;
        s += ev;
    }
    #pragma unroll
    for (int o = 32; o > 0; o >>= 1) s += __shfl_down(s, o);
    if (lane == 0) red_s[wid] = s;
    __syncthreads();
    float st = red_s[0];
    #pragma unroll
    for (int i = 1; i < 8; ++i) st += red_s[i];
    float inv = 1.0f / st;

    #pragma unroll
    for (int k = 0; k < EPT; ++k) {
        int e = tid + k * TPB;
        cbuf[(size_t)e * FF + f] = uvals[k] * inv;
    }
}

// K2 (R17-verbatim): block = tile of 32 same-relation edges; ping-pong W.
__global__ __launch_bounds__(TPB) void k2_out(
    const float* __restrict__ W, const float* __restrict__ cbuf,
    const int* __restrict__ perm, const int* __restrict__ tile_rel,
    float* __restrict__ out) {

    const int t    = blockIdx.x;   // 0..75
    const int tid  = threadIdx.x;
    const int wid  = tid >> 6;
    const int lane = tid & 63;

    const int r = tile_rel[t];     // single scalar load
    if (r < 0) return;             // empty tile (block-uniform)

    __shared__ float Wl[2][32 * DD];   // 2 x 8 KB ping-pong chunks
    __shared__ int   e_sh[TILE_E];

    if (tid < TILE_E) e_sh[tid] = perm[t * TILE_E + tid];
    __syncthreads();

    const float* __restrict__ Wr = W + (size_t)r * FF * DD;

    int eb[4];
    const float* ce[4];
    float4 acc[4];
    #pragma unroll
    for (int j = 0; j < 4; ++j) {
        eb[j]  = e_sh[wid * 4 + j];
        ce[j]  = cbuf + (size_t)(eb[j] >= 0 ? eb[j] : 0) * FF;
        acc[j] = make_float4(0.f, 0.f, 0.f, 0.f);
    }

    const int fg = lane >> 4;      // 0..3: f within a 4-group
    const int dq = lane & 15;      // 0..15: d-quad
    const int srow = tid >> 4;     // 0..31: staging row
    const int scol = tid & 15;     // 0..15: staging float4 col

    // stage chunk 0
    *(float4*)&Wl[0][srow * DD + scol * 4] =
        *(const float4*)&Wr[(size_t)srow * DD + scol * 4];
    __syncthreads();

    #pragma unroll
    for (int fc = 0; fc < FF / 32; ++fc) {   // 8 chunks of 32 features
        float4 nxt;
        if (fc < FF / 32 - 1)                // issue next load; hides under FMAs
            nxt = *(const float4*)
                &Wr[(size_t)((fc + 1) * 32 + srow) * DD + scol * 4];

        const float* Wc = Wl[fc & 1];
        #pragma unroll
        for (int i = 0; i < 8; ++i) {
            int lf = i * 4 + fg;                        // local f 0..31
            float4 w4 = *(const float4*)&Wc[lf * DD + dq * 4];
            int gf = fc * 32 + lf;
            #pragma unroll
            for (int j = 0; j < 4; ++j) {
                float c = ce[j][gf];                    // broadcast/16 lanes
                acc[j].x = fmaf(c, w4.x, acc[j].x);
                acc[j].y = fmaf(c, w4.y, acc[j].y);
                acc[j].z = fmaf(c, w4.z, acc[j].z);
                acc[j].w = fmaf(c, w4.w, acc[j].w);
            }
        }

        if (fc < FF / 32 - 1) {              // write other buffer, one barrier
            *(float4*)&Wl[(fc + 1) & 1][srow * DD + scol * 4] = nxt;
            __syncthreads();
        }
    }

    // per edge: sum the 4 f-groups (lanes l, l^16, l^32, l^48 share d-quad)
    #pragma unroll
    for (int j = 0; j < 4; ++j) {
        #pragma unroll
        for (int o = 16; o <= 32; o <<= 1) {
            acc[j].x += __shfl_xor(acc[j].x, o);
            acc[j].y += __shfl_xor(acc[j].y, o);
            acc[j].z += __shfl_xor(acc[j].z, o);
            acc[j].w += __shfl_xor(acc[j].w, o);
        }
        if (eb[j] >= 0 && fg == 0)
            *(float4*)&out[(size_t)eb[j] * DD + dq * 4] = acc[j];
    }
}

extern "C" void kernel_launch(void* const* d_in, const int* in_sizes, int n_in,
                              void* d_out, int out_size, void* d_ws, size_t ws_size,
                              hipStream_t stream) {
    const float* x  = (const float*)d_in[0];   // [N, F]
    const float* W  = (const float*)d_in[1];   // [R, F, D]
    const float* a  = (const float*)d_in[2];   // [2*D]
    const int* src  = (const int*)d_in[3];     // [E]
    const int* dst  = (const int*)d_in[4];     // [E]
    const int* rel  = (const int*)d_in[5];     // [E]
    float* out      = (float*)d_out;           // [E*D]

    char* wsb = (char*)d_ws;
    int*   perm     = (int*)wsb;
    int*   tile_rel = (int*)(wsb + 12288);
    float* cbuf     = (float*)(wsb + 16384);

    k1_coef<<<FF + 1, TPB, 0, stream>>>(x, W, a, src, dst, rel,
                                        cbuf, perm, tile_rel);
    // DIAGNOSTIC: K2 launched three times (idempotent).
    // dur = 19.9 + 2*(k2_inclusive)
    k2_out<<<K2_GRID, TPB, 0, stream>>>(W, cbuf, perm, tile_rel, out);
    k2_out<<<K2_GRID, TPB, 0, stream>>>(W, cbuf, perm, tile_rel, out);
    k2_out<<<K2_GRID, TPB, 0, stream>>>(W, cbuf, perm, tile_rel, out);
}

// Round 22
// 26.445 us; speedup vs baseline: 1.5898x; 1.5898x over previous
//
#include <hip/hip_runtime.h>
#include <hip/hip_bf16.h>

// Problem constants (match reference)
#define NN 1024
#define FF 256
#define DD 64
#define RR 11
#define EE 2048
#define ALPHA 0.2f
#define TPB 512
#define EPT (EE / TPB)          // 4 edges per thread in K1
#define TILE_E 32               // edges per K2 tile (same relation)
#define PERM_CAP 2432           // >= 2048 + 11*31, = 76*32
#define K2_GRID (PERM_CAP / TILE_E)  // 76

// ws layout (bytes):
//   0     : int perm[PERM_CAP]    (9728 B)
//   12288 : int tile_rel[K2_GRID] (304 B)  relation per tile, -1 = empty
//   16384 : float cbuf[EE*FF]     (2 MB, e-major: cbuf[e*FF+f])
//
// FINAL (R17 configuration, 19.9 us): two kernels; the kernel boundary is
// the device-wide sync. Session conclusion: dur is dominated by a ~10 us
// per-graph-node latency floor (R20/R21 node-count diagnostics), in-kernel
// work is ~2-4 us and already hidden under it.

// K1: blocks 0..255 own feature f=(b&7)*32+(b>>3) [XCD-grouped]. Stage
//     x[:,f] in LDS; p/q wave-dots; single-pass softmax (|v|<~2);
//     c[e,f]=exp(v)*xd/sum (e-major). Block 256: relation counting-sort
//     into 32-padded buckets + tile_rel table (concurrent, no straggler).
__global__ __launch_bounds__(TPB) void k1_coef(
    const float* __restrict__ x, const float* __restrict__ W,
    const float* __restrict__ a, const int* __restrict__ src,
    const int* __restrict__ dst, const int* __restrict__ rel,
    float* __restrict__ cbuf, int* __restrict__ perm,
    int* __restrict__ tile_rel) {

    const int b    = blockIdx.x;   // 0..256
    const int tid  = threadIdx.x;  // 0..511
    const int wid  = tid >> 6;     // 0..7
    const int lane = tid & 63;

    __shared__ int hist[16], base_sh[16], off_sh[16];

    if (b == FF) {
        // dedicated sort block
        if (tid < 16) hist[tid] = 0;
        __syncthreads();
        for (int e = tid; e < EE; e += TPB) atomicAdd(&hist[rel[e]], 1);
        __syncthreads();
        if (tid == 0) {
            int acc = 0;
            for (int r = 0; r < RR; ++r) {
                base_sh[r] = acc;
                off_sh[r] = acc;
                acc += (hist[r] + TILE_E - 1) & ~(TILE_E - 1);
            }
            int r = 0;
            for (int t = 0; t < K2_GRID; ++t) {
                while (r < RR && t * TILE_E >=
                       base_sh[r] + ((hist[r] + TILE_E - 1) & ~(TILE_E - 1)))
                    ++r;
                tile_rel[t] = (r < RR &&
                               t * TILE_E < base_sh[r] +
                               ((hist[r] + TILE_E - 1) & ~(TILE_E - 1)))
                              ? r : -1;
            }
        }
        __syncthreads();
        for (int i = tid; i < PERM_CAP; i += TPB) perm[i] = -1;
        __syncthreads();
        for (int e = tid; e < EE; e += TPB) {
            int pos = atomicAdd(&off_sh[rel[e]], 1);
            perm[pos] = e;
        }
        return;
    }

    const int f = ((b & 7) << 5) | (b >> 3);   // XCD-grouped feature

    __shared__ float xcol[NN];     // 4 KB: x[:, f]
    __shared__ float p_sh[RR], q_sh[RR];
    __shared__ float red_s[8];

    // stage column f of x (lines L2-shared within this XCD)
    for (int i = tid; i < NN; i += TPB) xcol[i] = x[(size_t)i * FF + f];

    // own-feature p/q
    for (int r = wid; r < RR; r += 8) {
        float w  = W[((size_t)r * FF + f) * DD + lane];
        float pa = w * a[lane];
        float qa = w * a[DD + lane];
        #pragma unroll
        for (int o = 32; o > 0; o >>= 1) {
            pa += __shfl_down(pa, o);
            qa += __shfl_down(qa, o);
        }
        if (lane == 0) { p_sh[r] = pa; q_sh[r] = qa; }
    }
    __syncthreads();   // xcol + p_sh/q_sh ready

    // single pass: u = exp(v)*xd, s = sum(exp(v))
    float uvals[EPT];
    float s = 0.0f;
    #pragma unroll
    for (int k = 0; k < EPT; ++k) {
        int e = tid + k * TPB;
        float xs = xcol[src[e]];
        float xd = xcol[dst[e]];
        int r = rel[e];
        float v = xs * p_sh[r] + xd * q_sh[r];
        v = v > 0.0f ? v : ALPHA * v;
        float ev = expf(v);
        uvals[k] = ev * xd;
        s += ev;
    }
    #pragma unroll
    for (int o = 32; o > 0; o >>= 1) s += __shfl_down(s, o);
    if (lane == 0) red_s[wid] = s;
    __syncthreads();
    float st = red_s[0];
    #pragma unroll
    for (int i = 1; i < 8; ++i) st += red_s[i];
    float inv = 1.0f / st;

    #pragma unroll
    for (int k = 0; k < EPT; ++k) {
        int e = tid + k * TPB;
        cbuf[(size_t)e * FF + f] = uvals[k] * inv;
    }
}

// K2: block = tile of 32 same-relation edges; 8 waves, wave = 4 edges.
//     tile_rel -> single scalar load; W_r streamed through ping-pong 8 KB
//     LDS chunks (one barrier per chunk, next load hidden under FMAs).
__global__ __launch_bounds__(TPB) void k2_out(
    const float* __restrict__ W, const float* __restrict__ cbuf,
    const int* __restrict__ perm, const int* __restrict__ tile_rel,
    float* __restrict__ out) {

    const int t    = blockIdx.x;   // 0..75
    const int tid  = threadIdx.x;
    const int wid  = tid >> 6;
    const int lane = tid & 63;

    const int r = tile_rel[t];     // single scalar load
    if (r < 0) return;             // empty tile (block-uniform)

    __shared__ float Wl[2][32 * DD];   // 2 x 8 KB ping-pong chunks
    __shared__ int   e_sh[TILE_E];

    if (tid < TILE_E) e_sh[tid] = perm[t * TILE_E + tid];
    __syncthreads();

    const float* __restrict__ Wr = W + (size_t)r * FF * DD;

    int eb[4];
    const float* ce[4];
    float4 acc[4];
    #pragma unroll
    for (int j = 0; j < 4; ++j) {
        eb[j]  = e_sh[wid * 4 + j];
        ce[j]  = cbuf + (size_t)(eb[j] >= 0 ? eb[j] : 0) * FF;
        acc[j] = make_float4(0.f, 0.f, 0.f, 0.f);
    }

    const int fg = lane >> 4;      // 0..3: f within a 4-group
    const int dq = lane & 15;      // 0..15: d-quad
    const int srow = tid >> 4;     // 0..31: staging row
    const int scol = tid & 15;     // 0..15: staging float4 col

    // stage chunk 0
    *(float4*)&Wl[0][srow * DD + scol * 4] =
        *(const float4*)&Wr[(size_t)srow * DD + scol * 4];
    __syncthreads();

    #pragma unroll
    for (int fc = 0; fc < FF / 32; ++fc) {   // 8 chunks of 32 features
        float4 nxt;
        if (fc < FF / 32 - 1)                // issue next load; hides under FMAs
            nxt = *(const float4*)
                &Wr[(size_t)((fc + 1) * 32 + srow) * DD + scol * 4];

        const float* Wc = Wl[fc & 1];
        #pragma unroll
        for (int i = 0; i < 8; ++i) {
            int lf = i * 4 + fg;                        // local f 0..31
            float4 w4 = *(const float4*)&Wc[lf * DD + dq * 4];
            int gf = fc * 32 + lf;
            #pragma unroll
            for (int j = 0; j < 4; ++j) {
                float c = ce[j][gf];                    // broadcast/16 lanes
                acc[j].x = fmaf(c, w4.x, acc[j].x);
                acc[j].y = fmaf(c, w4.y, acc[j].y);
                acc[j].z = fmaf(c, w4.z, acc[j].z);
                acc[j].w = fmaf(c, w4.w, acc[j].w);
            }
        }

        if (fc < FF / 32 - 1) {              // write other buffer, one barrier
            *(float4*)&Wl[(fc + 1) & 1][srow * DD + scol * 4] = nxt;
            __syncthreads();
        }
    }

    // per edge: sum the 4 f-groups (lanes l, l^16, l^32, l^48 share d-quad)
    #pragma unroll
    for (int j = 0; j < 4; ++j) {
        #pragma unroll
        for (int o = 16; o <= 32; o <<= 1) {
            acc[j].x += __shfl_xor(acc[j].x, o);
            acc[j].y += __shfl_xor(acc[j].y, o);
            acc[j].z += __shfl_xor(acc[j].z, o);
            acc[j].w += __shfl_xor(acc[j].w, o);
        }
        if (eb[j] >= 0 && fg == 0)
            *(float4*)&out[(size_t)eb[j] * DD + dq * 4] = acc[j];
    }
}

extern "C" void kernel_launch(void* const* d_in, const int* in_sizes, int n_in,
                              void* d_out, int out_size, void* d_ws, size_t ws_size,
                              hipStream_t stream) {
    const float* x  = (const float*)d_in[0];   // [N, F]
    const float* W  = (const float*)d_in[1];   // [R, F, D]
    const float* a  = (const float*)d_in[2];   // [2*D]
    const int* src  = (const int*)d_in[3];     // [E]
    const int* dst  = (const int*)d_in[4];     // [E]
    const int* rel  = (const int*)d_in[5];     // [E]
    float* out      = (float*)d_out;           // [E*D]

    char* wsb = (char*)d_ws;
    int*   perm     = (int*)wsb;
    int*   tile_rel = (int*)(wsb + 12288);
    float* cbuf     = (float*)(wsb + 16384);

    k1_coef<<<FF + 1, TPB, 0, stream>>>(x, W, a, src, dst, rel,
                                        cbuf, perm, tile_rel);
    k2_out<<<K2_GRID, TPB, 0, stream>>>(W, cbuf, perm, tile_rel, out);
}